// Round 10
// baseline (318.747 us; speedup 1.0000x reference)
//
#include <hip/hip_runtime.h>

namespace {

constexpr int HH  = 48;
constexpr int DIM = 384;
constexpr int NH  = 6;
constexpr int K3  = 27;
constexpr float L2E    = 1.44269504088896f;
constexpr float SCALE2 = 0.125f * L2E;          // 64^-0.5 * log2(e)

constexpr int TT     = 4;
constexpr int TILES1 = HH / TT;                 // 12
constexpr int TILES  = TILES1 * TILES1 * TILES1;// 1728
constexpr int NBLK   = 2 * NH * TILES * 2;      // 41472 (div by 8); 2 waves/block

typedef _Float16 half8  __attribute__((ext_vector_type(8)));
typedef _Float16 half2v __attribute__((ext_vector_type(2)));
typedef __fp16   fp16x2 __attribute__((ext_vector_type(2)));
typedef float    floatx4 __attribute__((ext_vector_type(4)));

__device__ __forceinline__ half2v pk(float a, float b) {
    fp16x2 t = __builtin_amdgcn_cvt_pkrtz(a, b);
    return __builtin_bit_cast(half2v, t);
}

__global__ __launch_bounds__(128, 5)
void natten_direct(const float* __restrict__ q, const float* __restrict__ k,
                   const float* __restrict__ rpb, const float* __restrict__ vv,
                   float* __restrict__ out)
{
    // all LDS is WAVE-LOCAL regions; no __syncthreads in this kernel
    __shared__ float  logit_lds[2 * 16 * 28];   // 3584 B (per-wave 16x28)
    __shared__ float4 rv_lds[2 * K3];           //  864 B (per-wave copy)

    const int bid0 = blockIdx.x;
    const int bid  = (bid0 & 7) * (NBLK / 8) + (bid0 >> 3);   // bijective XCD swizzle

    const int mhalf = bid & 1;
    const int n     = (bid >> 1) % NH;
    const int tile  = (bid / (2 * NH)) % TILES;
    const int b     = bid / (2 * NH * TILES);
    const int tz = (tile % TILES1) * TT;
    const int ty = ((tile / TILES1) % TILES1) * TT;
    const int tx = (tile / (TILES1 * TILES1)) * TT;

    const int tid  = threadIdx.x;
    const int w    = tid >> 6, lane = tid & 63;
    const int lrow = lane & 15, lgrp = lane >> 4;
    const int mtile = mhalf * 2 + w;            // this wave's query x-offset (0..3)

    // ---- q -> A fragments (row = lrow, k-chunk = lgrp) ----
    const float* qp = q + (size_t)b * (HH * HH * HH) * DIM
        + (size_t)(((tx + mtile) * 48 + (ty + (lrow >> 2))) * 48 + (tz + (lrow & 3))) * DIM
        + n * 64 + lgrp * 8;
    const float4 qf0 = ((const float4*)qp)[0];
    const float4 qf1 = ((const float4*)qp)[1];
    const float4 qg0 = ((const float4*)(qp + 32))[0];
    const float4 qg1 = ((const float4*)(qp + 32))[1];
    half8 a0, a1;
    ((half2v*)&a0)[0] = pk(qf0.x, qf0.y);
    ((half2v*)&a0)[1] = pk(qf0.z, qf0.w);
    ((half2v*)&a0)[2] = pk(qf1.x, qf1.y);
    ((half2v*)&a0)[3] = pk(qf1.z, qf1.w);
    ((half2v*)&a1)[0] = pk(qg0.x, qg0.y);
    ((half2v*)&a1)[1] = pk(qg0.z, qg0.w);
    ((half2v*)&a1)[2] = pk(qg1.x, qg1.y);
    ((half2v*)&a1)[3] = pk(qg1.z, qg1.w);

    // ---- GEMM: k read DIRECTLY from global into B fragments; 7 slabs of 16 cols ----
    // B fragment: col = lrow, k-chunk = lgrp. Slab nt covers cols mtile*36+nt*16+[0,16).
    const float* kb = k + (size_t)b * (HH * HH * HH) * DIM + n * 64;
    const unsigned cb = mtile * 36 + lrow;
    floatx4 acc[7];
    #pragma unroll
    for (int nt = 0; nt < 7; ++nt) {
        const unsigned col = cb + nt * 16;      // may exceed 215 for mtile=3; clamped, masked later
        const int cx = col / 36, r36 = col - cx * 36;
        const int cy = r36 / 6,  cz = r36 - cy * 6;
        const int cgx = min(max(tx + cx - 1, 0), 47);
        const int cgy = min(max(ty + cy - 1, 0), 47);
        const int cgz = min(max(tz + cz - 1, 0), 47);
        const float* s = kb + (size_t)((cgx * 48 + cgy) * 48 + cgz) * DIM + lgrp * 8;
        const float4 u0 = ((const float4*)s)[0];
        const float4 u1 = ((const float4*)s)[1];
        const float4 u2 = ((const float4*)(s + 32))[0];
        const float4 u3 = ((const float4*)(s + 32))[1];
        half8 b0, b1;
        ((half2v*)&b0)[0] = pk(u0.x, u0.y);
        ((half2v*)&b0)[1] = pk(u0.z, u0.w);
        ((half2v*)&b0)[2] = pk(u1.x, u1.y);
        ((half2v*)&b0)[3] = pk(u1.z, u1.w);
        ((half2v*)&b1)[0] = pk(u2.x, u2.y);
        ((half2v*)&b1)[1] = pk(u2.z, u2.w);
        ((half2v*)&b1)[2] = pk(u3.x, u3.y);
        ((half2v*)&b1)[3] = pk(u3.z, u3.w);
        floatx4 c = {0.f, 0.f, 0.f, 0.f};
        c = __builtin_amdgcn_mfma_f32_16x16x32_f16(a0, b0, c, 0, 0, 0);
        c = __builtin_amdgcn_mfma_f32_16x16x32_f16(a1, b1, c, 0, 0, 0);
        acc[nt] = c;
    }

    // ---- scatter banded entries -> wave-local [16][28]; OOB cols masked to 0 ----
    // rel = nt*16+lrow = rx*36+ry*6+rz; query row m=lgrp*4+r => di=rx, dj=ry-lgrp, dl=rz-r
    {
        const int ly6 = lrow >= 12 ? 2 : (lrow >= 6 ? 1 : 0);
        const int lz6 = lrow - ly6 * 6;
        const int base0 = w * 16 * 112 + (lgrp * 4) * 112;   // byte offset, row m(r=0)
        constexpr int Nx[7] = {0, 0, 0, 1, 1, 2, 2};
        constexpr int Ny[7] = {0, 2, 5, 2, 4, 1, 4};
        constexpr int Nz[7] = {0, 4, 2, 0, 4, 2, 0};
        #pragma unroll
        for (int nt = 0; nt < 7; ++nt) {
            int rz = lz6 + Nz[nt];
            int ry = ly6 + Ny[nt];
            if (rz >= 6) { rz -= 6; ry += 1; }
            int rx = Nx[nt];
            if (ry >= 6) { ry -= 6; rx += 1; }
            const int dj = ry - lgrp;
            if (rx <= 2 && (unsigned)dj <= 2u) {
                const bool vx = (unsigned)(tx + mtile + rx - 1) < 48u;
                const bool vy = (unsigned)(ty + ry - 1) < 48u;
                const bool vz = (unsigned)(tz + rz - 1) < 48u;
                const float fm = (vx && vy && vz) ? 1.f : 0.f;   // zero-pad semantics
                const int sl0 = (rx * 3 + dj) * 3 + rz;          // slot(r) = sl0 - r
                #pragma unroll
                for (int r = 0; r < 4; ++r) {
                    if ((unsigned)(rz - r) <= 2u) {
                        *(float*)((char*)logit_lds + base0 + r * 112 + (sl0 - r) * 4)
                            = acc[nt][r] * fm;
                    }
                }
            }
        }
    }

    // per-wave rpb/v table (no cross-wave sharing -> no barrier needed)
    if (lane < K3) {
        rv_lds[w * K3 + lane] = make_float4(vv[lane * 3], vv[lane * 3 + 1],
                                            vv[lane * 3 + 2], rpb[n * K3 + lane] * L2E);
    }
    // same-wave LDS write->read ordering is guaranteed by lgkmcnt (r8-proven pattern)

    // ---- softmax (exp2 domain): 4 lanes/query, 16 queries/wave ----
    {
        const int qi = lane >> 2, p = lane & 3;
        const float*  lp = logit_lds + w * 448 + qi * 28;
        const float4* rv = rv_lds + w * K3;
        float t[7];
        float mx = -1e30f;
        #pragma unroll
        for (int j = 0; j < 7; ++j) {
            const int o = p + 4 * j;
            if (o < K3) {
                t[j] = fmaf(lp[o], SCALE2, rv[o].w);
                mx = fmaxf(mx, t[j]);
            }
        }
        mx = fmaxf(mx, __shfl_xor(mx, 1));
        mx = fmaxf(mx, __shfl_xor(mx, 2));
        float den = 0.f, n0 = 0.f, n1 = 0.f, n2 = 0.f;
        #pragma unroll
        for (int j = 0; j < 7; ++j) {
            const int o = p + 4 * j;
            if (o < K3) {
                const float e = __builtin_amdgcn_exp2f(t[j] - mx);
                const float4 rvo = rv[o];
                den += e;
                n0 = fmaf(e, rvo.x, n0);
                n1 = fmaf(e, rvo.y, n1);
                n2 = fmaf(e, rvo.z, n2);
            }
        }
        den += __shfl_xor(den, 1); den += __shfl_xor(den, 2);
        n0  += __shfl_xor(n0, 1);  n0  += __shfl_xor(n0, 2);
        n1  += __shfl_xor(n1, 1);  n1  += __shfl_xor(n1, 2);
        n2  += __shfl_xor(n2, 1);  n2  += __shfl_xor(n2, 2);
        if (p < 3) {
            const float res = (p == 0 ? n0 : (p == 1 ? n1 : n2)) / den;
            out[((size_t)(b * 18 + n * 3 + p) * HH + (tx + mtile)) * (size_t)(HH * HH)
                + (size_t)(ty + (qi >> 2)) * HH + (tz + (qi & 3))] = res;
        }
    }
}

} // namespace

extern "C" void kernel_launch(void* const* d_in, const int* in_sizes, int n_in,
                              void* d_out, int out_size, void* d_ws, size_t ws_size,
                              hipStream_t stream)
{
    (void)in_sizes; (void)n_in; (void)d_ws; (void)ws_size; (void)out_size;
    const float* q   = (const float*)d_in[0];
    const float* k   = (const float*)d_in[1];
    const float* rpb = (const float*)d_in[2];
    const float* vv  = (const float*)d_in[3];
    float* out = (float*)d_out;

    natten_direct<<<dim3(NBLK), dim3(128), 0, stream>>>(q, k, rpb, vv, out);
}